// Round 11
// baseline (37672.327 us; speedup 1.0000x reference)
//
#include <hip/hip_runtime.h>
#include <math.h>

// ---------------------------------------------------------------------------
// PointerNet rollout on MI355X — round-11.
// r9 PMC: VALUBusy 18%, HBM 3%, Occ 25% -> issue-starved at 2 waves/SIMD.
// attn: 1024 thr (4 waves/SIMD), 32 groups x 8 rows, q/V in regs, compaction,
// depth-1 prefetch, no pairing (VGPR<=128). lstm: (8,32) x 512 thr (2 w/SIMD,
// r8 W-traffic). Gates/logit chains bit-identical to r8/r10 passing kernels.
// ---------------------------------------------------------------------------

#define Bz 256
#define Sz 256
#define Ez 128
#define Hz 512
#define NEGV -1e9f
#define BH (Bz*Hz)

__device__ float g_encout[Bz*Sz*Hz];
__device__ float g_glref[Bz*Sz*Hz];
__device__ float g_ptref[Bz*Sz*Hz];
__device__ float g_xpe[256*2048];
__device__ float g_xpd[257*2048];
__device__ float g_h[2*BH];
__device__ float g_c[BH];
__device__ int g_ptrbuf[Bz];
__device__ unsigned g_keys[2*Sz];
__device__ unsigned char g_mask[Bz*Sz];

__device__ __forceinline__ unsigned rotl32(unsigned v, int d){ return (v<<d)|(v>>(32-d)); }

__device__ __forceinline__ void tf2x32(unsigned k0, unsigned k1, unsigned x0, unsigned x1,
                                       unsigned &o0, unsigned &o1){
  unsigned ks2 = k0 ^ k1 ^ 0x1BD11BDAu;
  x0 += k0; x1 += k1;
#define TFR(r) { x0 += x1; x1 = rotl32(x1,(r)); x1 ^= x0; }
  TFR(13) TFR(15) TFR(26) TFR(6)
  x0 += k1; x1 += ks2 + 1u;
  TFR(17) TFR(29) TFR(16) TFR(24)
  x0 += ks2; x1 += k0 + 2u;
  TFR(13) TFR(15) TFR(26) TFR(6)
  x0 += k0; x1 += k1 + 3u;
  TFR(17) TFR(29) TFR(16) TFR(24)
  x0 += k1; x1 += ks2 + 4u;
  TFR(13) TFR(15) TFR(26) TFR(6)
  x0 += ks2; x1 += k0 + 5u;
#undef TFR
  o0 = x0; o1 = x1;
}

__device__ __forceinline__ unsigned rng_bits(unsigned ka, unsigned kb, unsigned idx){
  unsigned o0,o1; tf2x32(ka,kb, 0u, idx, o0,o1);
  return o0 ^ o1;
}

// ---------------------------------------------------------------------------
__global__ __launch_bounds__(256) void init_kernel(){
  int i = blockIdx.x*256 + threadIdx.x;
  if (i < BH){ g_h[i] = 0.f; g_c[i] = 0.f; }
  if (i < Bz*Sz) g_mask[i] = 0;
  if (i < Sz){
    unsigned o0,o1; tf2x32(0u,1u, 0u, (unsigned)i, o0,o1);
    g_keys[2*i] = o0; g_keys[2*i+1] = o1;
  }
}

// ---------------------------------------------------------------------------
__global__ __launch_bounds__(256) void xproj_kernel(
    const float* __restrict__ Wih, const float* __restrict__ bias,
    const float* __restrict__ emb, const float* __restrict__ dstart,
    int dst)
{
  float* Xp = dst ? g_xpd : g_xpe;
  int c = blockIdx.x;
  int row = blockIdx.y*256 + threadIdx.x;
  __shared__ float xs[Ez];
  if (threadIdx.x < Ez) xs[threadIdx.x] = (c < 256) ? emb[c*Ez + threadIdx.x]
                                                    : dstart[threadIdx.x];
  __syncthreads();
  float a = bias[row];
  const float* w = Wih + (size_t)row*Ez;
  #pragma unroll 8
  for (int k = 0; k < Ez; k++) a = fmaf(xs[k], w[k], a);
  Xp[(size_t)c*2048 + row] = a;
}

// ---------------------------------------------------------------------------
// LSTM step v6: grid (8,32) x 512 thr. Block = 32 b x 64 gate-rows; thread =
// 1 b x 4 gates (bp 0..31, jj 0..15). Same W traffic as r8, 2 waves/SIMD.
// k-ascending per-acc chains -> bit-identical gates.
// ---------------------------------------------------------------------------
__global__ __launch_bounds__(512) void lstm_step(
    const float* __restrict__ Whh,   // [2048][512]
    const int*   __restrict__ inputs,// [Bz][Sz]
    int t, int is_dec, int hsel)
{
  __shared__ float A_lds[32][36];   // [b][k]
  __shared__ float W_lds[64][36];   // [row][k], row = gate*16 + jj

  const float* h_in = g_h + (size_t)hsel*BH;
  float*       h_out = g_h + (size_t)(hsel^1)*BH;
  const float* Xp = is_dec ? g_xpd : g_xpe;

  int tid = threadIdx.x;
  int bt = blockIdx.x;     // 0..7 (32 b)
  int jt = blockIdx.y;     // 0..31 (16 j)
  int jj = tid & 15;
  int bp = tid >> 4;       // 0..31 (1 b)
  int jglob = jt*16 + jj;
  int b = bt*32 + bp;

  int c;
  if (is_dec) c = (t == 0) ? 256 : inputs[b*Sz + g_ptrbuf[b]];
  else        c = inputs[b*Sz + t];

  float acc[4];
  {
    const float* xa = Xp + (size_t)c*2048;
    #pragma unroll
    for (int g=0; g<4; g++) acc[g] = xa[g*Hz + jglob];
  }

  int sr = tid >> 3;          // 0..63
  int sk = (tid & 7) * 4;
  int wrow_g = (sr >> 4)*Hz + jt*16 + (sr & 15);

  for (int kc = 0; kc < 16; kc++){
    int k0 = kc*32;
    __syncthreads();
    if (tid < 256){
      float4 av = *(const float4*)(h_in + (size_t)(bt*32 + (tid>>3))*Hz + k0 + sk);
      *(float4*)&A_lds[tid>>3][sk] = av;
    }
    {
      const float* ws = Whh + (size_t)wrow_g*Hz + k0 + sk;
      float4 w0 = *(const float4*)ws;
      *(float4*)&W_lds[sr][sk] = w0;
    }
    __syncthreads();
    #pragma unroll
    for (int k4 = 0; k4 < 8; k4++){
      float4 w0 = *(const float4*)&W_lds[jj      ][k4*4];
      float4 w1 = *(const float4*)&W_lds[16 + jj ][k4*4];
      float4 w2 = *(const float4*)&W_lds[32 + jj ][k4*4];
      float4 w3 = *(const float4*)&W_lds[48 + jj ][k4*4];
      float4 a0 = *(const float4*)&A_lds[bp][k4*4];
#define LSTEP(c_) \
      acc[0]=fmaf(a0.c_,w0.c_,acc[0]); acc[1]=fmaf(a0.c_,w1.c_,acc[1]); \
      acc[2]=fmaf(a0.c_,w2.c_,acc[2]); acc[3]=fmaf(a0.c_,w3.c_,acc[3]);
      LSTEP(x) LSTEP(y) LSTEP(z) LSTEP(w)
#undef LSTEP
    }
  }

  float gi = acc[0], gf = acc[1], gg = acc[2], go = acc[3];
  float co = g_c[(size_t)b*Hz + jglob];
  float si = 1.f/(1.f + expf(-gi));
  float sf = 1.f/(1.f + expf(-gf));
  float so = 1.f/(1.f + expf(-go));
  float cn = sf*co + si*tanhf(gg);
  float hn = so*tanhf(cn);
  g_c[(size_t)b*Hz + jglob] = cn;
  h_out[(size_t)b*Hz + jglob] = hn;
  if (!is_dec) g_encout[((size_t)b*Sz + t)*Hz + jglob] = hn;
}

// ---------------------------------------------------------------------------
// ref projections: C[65536][512] = enc_out @ W^T + b. 64x64 tile (r8 verbatim).
// ---------------------------------------------------------------------------
__global__ __launch_bounds__(256) void gemm_ref(
    const float* __restrict__ W, const float* __restrict__ bias, int dst_id)
{
  const float* A = g_encout;
  float*       C = (dst_id == 1) ? g_glref : g_ptref;
  __shared__ float As[32][68];
  __shared__ float Ws[32][68];
  int tid = threadIdx.x;
  int mt = blockIdx.x * 64, nt = blockIdx.y * 64;
  int tm = (tid & 15) * 4, tn = (tid >> 4) * 4;
  float acc[4][4] = {};
  int lr = tid >> 2;
  int lk = (tid & 3) * 8;

  for (int kc = 0; kc < 16; kc++){
    int k0 = kc*32;
    __syncthreads();
    {
      const float* ar = A + (size_t)(mt + lr)*Hz + k0 + lk;
      float4 a0 = *(const float4*)ar, a1 = *(const float4*)(ar+4);
      As[lk+0][lr]=a0.x; As[lk+1][lr]=a0.y; As[lk+2][lr]=a0.z; As[lk+3][lr]=a0.w;
      As[lk+4][lr]=a1.x; As[lk+5][lr]=a1.y; As[lk+6][lr]=a1.z; As[lk+7][lr]=a1.w;
      const float* wrp = W + (size_t)(nt + lr)*Hz + k0 + lk;
      float4 w0 = *(const float4*)wrp, w1 = *(const float4*)(wrp+4);
      Ws[lk+0][lr]=w0.x; Ws[lk+1][lr]=w0.y; Ws[lk+2][lr]=w0.z; Ws[lk+3][lr]=w0.w;
      Ws[lk+4][lr]=w1.x; Ws[lk+5][lr]=w1.y; Ws[lk+6][lr]=w1.z; Ws[lk+7][lr]=w1.w;
    }
    __syncthreads();
    #pragma unroll
    for (int k=0;k<32;k++){
      float4 av = *(const float4*)&As[k][tm];
      float4 wv = *(const float4*)&Ws[k][tn];
      acc[0][0]=fmaf(av.x,wv.x,acc[0][0]); acc[0][1]=fmaf(av.x,wv.y,acc[0][1]);
      acc[0][2]=fmaf(av.x,wv.z,acc[0][2]); acc[0][3]=fmaf(av.x,wv.w,acc[0][3]);
      acc[1][0]=fmaf(av.y,wv.x,acc[1][0]); acc[1][1]=fmaf(av.y,wv.y,acc[1][1]);
      acc[1][2]=fmaf(av.y,wv.z,acc[1][2]); acc[1][3]=fmaf(av.y,wv.w,acc[1][3]);
      acc[2][0]=fmaf(av.z,wv.x,acc[2][0]); acc[2][1]=fmaf(av.z,wv.y,acc[2][1]);
      acc[2][2]=fmaf(av.z,wv.z,acc[2][2]); acc[2][3]=fmaf(av.z,wv.w,acc[2][3]);
      acc[3][0]=fmaf(av.w,wv.x,acc[3][0]); acc[3][1]=fmaf(av.w,wv.y,acc[3][1]);
      acc[3][2]=fmaf(av.w,wv.z,acc[3][2]); acc[3][3]=fmaf(av.w,wv.w,acc[3][3]);
    }
  }
  float b0v = bias[nt+tn+0], b1v = bias[nt+tn+1], b2v = bias[nt+tn+2], b3v = bias[nt+tn+3];
  #pragma unroll
  for (int i=0;i<4;i++){
    float4 o;
    o.x = acc[i][0] + b0v; o.y = acc[i][1] + b1v;
    o.z = acc[i][2] + b2v; o.w = acc[i][3] + b3v;
    *(float4*)(C + (size_t)(mt + tm + i)*Hz + nt + tn) = o;
  }
}

// exact r8 logit chain
__device__ __forceinline__ float logit_chain(
    const float4& x0, const float4& x1, const float4& x2, const float4& x3,
    const float4& q0, const float4& q1, const float4& q2, const float4& q3,
    const float4& v0, const float4& v1, const float4& v2, const float4& v3)
{
  float p = 0.f;
  p = fmaf(v0.x, tanhf(q0.x + x0.x), p); p = fmaf(v0.y, tanhf(q0.y + x0.y), p);
  p = fmaf(v0.z, tanhf(q0.z + x0.z), p); p = fmaf(v0.w, tanhf(q0.w + x0.w), p);
  p = fmaf(v1.x, tanhf(q1.x + x1.x), p); p = fmaf(v1.y, tanhf(q1.y + x1.y), p);
  p = fmaf(v1.z, tanhf(q1.z + x1.z), p); p = fmaf(v1.w, tanhf(q1.w + x1.w), p);
  p = fmaf(v2.x, tanhf(q2.x + x2.x), p); p = fmaf(v2.y, tanhf(q2.y + x2.y), p);
  p = fmaf(v2.z, tanhf(q2.z + x2.z), p); p = fmaf(v2.w, tanhf(q2.w + x2.w), p);
  p = fmaf(v3.x, tanhf(q3.x + x3.x), p); p = fmaf(v3.y, tanhf(q3.y + x3.y), p);
  p = fmaf(v3.z, tanhf(q3.z + x3.z), p); p = fmaf(v3.w, tanhf(q3.w + x3.w), p);
  return p;
}

// ---------------------------------------------------------------------------
// Fused attention step: 1024 thr = 16 waves = 32 groups x 32 lanes.
// Group g owns rows g*8 .. g*8+7 (compacted). q/V hoisted to regs.
// ---------------------------------------------------------------------------
__global__ __launch_bounds__(1024) void attn_step(
    const float* __restrict__ gl_Wq, const float* __restrict__ gl_bq,
    const float* __restrict__ gl_V,
    const float* __restrict__ pt_Wq, const float* __restrict__ pt_bq,
    const float* __restrict__ pt_V,
    int t, int hsel2, float* __restrict__ out)
{
  int b = blockIdx.x, tid = threadIdx.x;
  int wave = tid >> 6, lane64 = tid & 63;
  int g = tid >> 5, lane = tid & 31;

  __shared__ __align__(16) float hq[Hz];
  __shared__ __align__(16) float q2s[Hz];
  __shared__ __align__(16) float qgs[Hz];
  __shared__ __align__(16) float qps[Hz];
  __shared__ __align__(16) float vgl[Hz];
  __shared__ __align__(16) float vpt[Hz];
  __shared__ float part[32][513];     // 65.7 KB
  __shared__ float m_arr[32];
  __shared__ float l_arr[32];
  __shared__ int   rlist[32][8];
  __shared__ float slog[Sz];
  __shared__ float redy[16]; __shared__ int redi[16];
  __shared__ float redm[16]; __shared__ float redsum[16];

  if (tid < Hz){
    hq[tid]  = g_h[(size_t)hsel2*BH + (size_t)b*Hz + tid];
    vgl[tid] = gl_V[tid];
    vpt[tid] = pt_V[tid];
  }
  __syncthreads();

  const unsigned char* mrow = g_mask + b*Sz;

  // ---- compacted row list per group (group g owns rows g*8..g*8+7)
  int cnt;
  {
    bool un = (lane < 8) ? (mrow[g*8 + lane] == 0) : false;
    unsigned long long bal = __ballot(un);
    unsigned m8 = (unsigned)(bal >> ((g & 1) ? 32 : 0)) & 0xFFu;
    cnt = __popc(m8);
    if (lane < 8){
      if (un){
        int rank = __popc(m8 & ((1u << lane) - 1u));
        rlist[g][rank] = g*8 + lane;
      } else {
        slog[g*8 + lane] = NEGV;
      }
    }
  }

  // ---- q2 = gl_Wq @ h + gl_bq  (wave w: j = w*32..w*32+31, unroll 2)
  {
    float hv[8];
    #pragma unroll
    for (int i=0;i<8;i++) hv[i] = hq[lane64*8 + i];
    for (int jj=0;jj<32;jj+=2){
      int j0 = wave*32 + jj;
      const float* wr0 = gl_Wq + (size_t)j0*Hz + lane64*8;
      const float* wr1 = wr0 + Hz;
      float4 A0 = *(const float4*)wr0, A1 = *(const float4*)(wr0+4);
      float4 B0 = *(const float4*)wr1, B1 = *(const float4*)(wr1+4);
      float p0 = 0.f, p1 = 0.f;
      p0 = fmaf(hv[0], A0.x, p0); p0 = fmaf(hv[1], A0.y, p0);
      p0 = fmaf(hv[2], A0.z, p0); p0 = fmaf(hv[3], A0.w, p0);
      p0 = fmaf(hv[4], A1.x, p0); p0 = fmaf(hv[5], A1.y, p0);
      p0 = fmaf(hv[6], A1.z, p0); p0 = fmaf(hv[7], A1.w, p0);
      p1 = fmaf(hv[0], B0.x, p1); p1 = fmaf(hv[1], B0.y, p1);
      p1 = fmaf(hv[2], B0.z, p1); p1 = fmaf(hv[3], B0.w, p1);
      p1 = fmaf(hv[4], B1.x, p1); p1 = fmaf(hv[5], B1.y, p1);
      p1 = fmaf(hv[6], B1.z, p1); p1 = fmaf(hv[7], B1.w, p1);
      #pragma unroll
      for (int off=32; off; off>>=1) p0 += __shfl_xor(p0, off);
      #pragma unroll
      for (int off=32; off; off>>=1) p1 += __shfl_xor(p1, off);
      if (lane64 == 0){ q2s[j0] = p0 + gl_bq[j0]; q2s[j0+1] = p1 + gl_bq[j0+1]; }
    }
  }
  __syncthreads();

  // ---- glimpse: online softmax, q/V in regs, depth-1 prefetch
  const float* glbase = g_glref + (size_t)b*Sz*Hz;
  {
    float4 q0 = *(const float4*)&q2s[lane*4];
    float4 q1 = *(const float4*)&q2s[(lane+32)*4];
    float4 q2 = *(const float4*)&q2s[(lane+64)*4];
    float4 q3 = *(const float4*)&q2s[(lane+96)*4];
    float4 v0 = *(const float4*)&vgl[lane*4];
    float4 v1 = *(const float4*)&vgl[(lane+32)*4];
    float4 v2 = *(const float4*)&vgl[(lane+64)*4];
    float4 v3 = *(const float4*)&vgl[(lane+96)*4];

    float m_g = -INFINITY, l_g = 0.f;
    float4 racc[4];
    { float4 z = {0.f,0.f,0.f,0.f}; racc[0]=z; racc[1]=z; racc[2]=z; racc[3]=z; }

    float4 xn0, xn1, xn2, xn3;
    if (cnt > 0){
      const float4* rp = (const float4*)(glbase + (size_t)rlist[g][0]*Hz);
      xn0 = rp[lane]; xn1 = rp[lane+32]; xn2 = rp[lane+64]; xn3 = rp[lane+96];
    }
    for (int i = 0; i < cnt; i++){
      float4 x0 = xn0, x1 = xn1, x2 = xn2, x3 = xn3;
      if (i + 1 < cnt){
        const float4* rp = (const float4*)(glbase + (size_t)rlist[g][i+1]*Hz);
        xn0 = rp[lane]; xn1 = rp[lane+32]; xn2 = rp[lane+64]; xn3 = rp[lane+96];
      }
      float p = logit_chain(x0,x1,x2,x3, q0,q1,q2,q3, v0,v1,v2,v3);
      #pragma unroll
      for (int off=16; off; off>>=1) p += __shfl_xor(p, off, 32);
      float lgv = p;
      if (lgv > m_g){
        float r_ = expf(m_g - lgv);
        l_g *= r_;
        racc[0].x*=r_; racc[0].y*=r_; racc[0].z*=r_; racc[0].w*=r_;
        racc[1].x*=r_; racc[1].y*=r_; racc[1].z*=r_; racc[1].w*=r_;
        racc[2].x*=r_; racc[2].y*=r_; racc[2].z*=r_; racc[2].w*=r_;
        racc[3].x*=r_; racc[3].y*=r_; racc[3].z*=r_; racc[3].w*=r_;
        m_g = lgv;
      }
      float pr = expf(lgv - m_g);
      l_g += pr;
      racc[0].x=fmaf(pr,x0.x,racc[0].x); racc[0].y=fmaf(pr,x0.y,racc[0].y);
      racc[0].z=fmaf(pr,x0.z,racc[0].z); racc[0].w=fmaf(pr,x0.w,racc[0].w);
      racc[1].x=fmaf(pr,x1.x,racc[1].x); racc[1].y=fmaf(pr,x1.y,racc[1].y);
      racc[1].z=fmaf(pr,x1.z,racc[1].z); racc[1].w=fmaf(pr,x1.w,racc[1].w);
      racc[2].x=fmaf(pr,x2.x,racc[2].x); racc[2].y=fmaf(pr,x2.y,racc[2].y);
      racc[2].z=fmaf(pr,x2.z,racc[2].z); racc[2].w=fmaf(pr,x2.w,racc[2].w);
      racc[3].x=fmaf(pr,x3.x,racc[3].x); racc[3].y=fmaf(pr,x3.y,racc[3].y);
      racc[3].z=fmaf(pr,x3.z,racc[3].z); racc[3].w=fmaf(pr,x3.w,racc[3].w);
    }
    if (lane == 0){ m_arr[g] = m_g; l_arr[g] = l_g; }
    part[g][4*lane+  0] = racc[0].x; part[g][4*lane+  1] = racc[0].y;
    part[g][4*lane+  2] = racc[0].z; part[g][4*lane+  3] = racc[0].w;
    part[g][4*lane+128] = racc[1].x; part[g][4*lane+129] = racc[1].y;
    part[g][4*lane+130] = racc[1].z; part[g][4*lane+131] = racc[1].w;
    part[g][4*lane+256] = racc[2].x; part[g][4*lane+257] = racc[2].y;
    part[g][4*lane+258] = racc[2].z; part[g][4*lane+259] = racc[2].w;
    part[g][4*lane+384] = racc[3].x; part[g][4*lane+385] = racc[3].y;
    part[g][4*lane+386] = racc[3].z; part[g][4*lane+387] = racc[3].w;
  }
  __syncthreads();

  // ---- merge group partials -> qg
  if (tid < Hz){
    float M = m_arr[0];
    #pragma unroll
    for (int gg=1; gg<32; gg++) M = fmaxf(M, m_arr[gg]);
    float num = 0.f, den = 0.f;
    #pragma unroll
    for (int gg=0; gg<32; gg++){
      float w = expf(m_arr[gg] - M);
      num = fmaf(w, part[gg][tid], num);
      den = fmaf(w, l_arr[gg], den);
    }
    qgs[tid] = num / den;
  }
  __syncthreads();

  // ---- qpt = pt_Wq @ qg + pt_bq (unroll 2)
  {
    float qv[8];
    #pragma unroll
    for (int i=0;i<8;i++) qv[i] = qgs[lane64*8 + i];
    for (int jj=0;jj<32;jj+=2){
      int j0 = wave*32 + jj;
      const float* wr0 = pt_Wq + (size_t)j0*Hz + lane64*8;
      const float* wr1 = wr0 + Hz;
      float4 A0 = *(const float4*)wr0, A1 = *(const float4*)(wr0+4);
      float4 B0 = *(const float4*)wr1, B1 = *(const float4*)(wr1+4);
      float p0 = 0.f, p1 = 0.f;
      p0 = fmaf(qv[0], A0.x, p0); p0 = fmaf(qv[1], A0.y, p0);
      p0 = fmaf(qv[2], A0.z, p0); p0 = fmaf(qv[3], A0.w, p0);
      p0 = fmaf(qv[4], A1.x, p0); p0 = fmaf(qv[5], A1.y, p0);
      p0 = fmaf(qv[6], A1.z, p0); p0 = fmaf(qv[7], A1.w, p0);
      p1 = fmaf(qv[0], B0.x, p1); p1 = fmaf(qv[1], B0.y, p1);
      p1 = fmaf(qv[2], B0.z, p1); p1 = fmaf(qv[3], B0.w, p1);
      p1 = fmaf(qv[4], B1.x, p1); p1 = fmaf(qv[5], B1.y, p1);
      p1 = fmaf(qv[6], B1.z, p1); p1 = fmaf(qv[7], B1.w, p1);
      #pragma unroll
      for (int off=32; off; off>>=1) p0 += __shfl_xor(p0, off);
      #pragma unroll
      for (int off=32; off; off>>=1) p1 += __shfl_xor(p1, off);
      if (lane64 == 0){ qps[j0] = p0 + pt_bq[j0]; qps[j0+1] = p1 + pt_bq[j0+1]; }
    }
  }
  __syncthreads();

  // ---- pointer pass: compacted rows, q/V in regs, depth-1 prefetch
  const float* ptbase = g_ptref + (size_t)b*Sz*Hz;
  {
    float4 q0 = *(const float4*)&qps[lane*4];
    float4 q1 = *(const float4*)&qps[(lane+32)*4];
    float4 q2 = *(const float4*)&qps[(lane+64)*4];
    float4 q3 = *(const float4*)&qps[(lane+96)*4];
    float4 v0 = *(const float4*)&vpt[lane*4];
    float4 v1 = *(const float4*)&vpt[(lane+32)*4];
    float4 v2 = *(const float4*)&vpt[(lane+64)*4];
    float4 v3 = *(const float4*)&vpt[(lane+96)*4];

    float4 xn0, xn1, xn2, xn3;
    if (cnt > 0){
      const float4* rp = (const float4*)(ptbase + (size_t)rlist[g][0]*Hz);
      xn0 = rp[lane]; xn1 = rp[lane+32]; xn2 = rp[lane+64]; xn3 = rp[lane+96];
    }
    for (int i = 0; i < cnt; i++){
      int s = rlist[g][i];
      float4 x0 = xn0, x1 = xn1, x2 = xn2, x3 = xn3;
      if (i + 1 < cnt){
        const float4* rp = (const float4*)(ptbase + (size_t)rlist[g][i+1]*Hz);
        xn0 = rp[lane]; xn1 = rp[lane+32]; xn2 = rp[lane+64]; xn3 = rp[lane+96];
      }
      float p = logit_chain(x0,x1,x2,x3, q0,q1,q2,q3, v0,v1,v2,v3);
      #pragma unroll
      for (int off=16; off; off>>=1) p += __shfl_xor(p, off, 32);
      if (lane == 0) slog[s] = 10.f * tanhf(p);
    }
  }
  __syncthreads();

  // ---- Gumbel-max sample (threads 0..255 own s = tid)
  float lg = NEGV, y = -INFINITY;
  if (tid < Sz){
    lg = slog[tid];
    unsigned bits = rng_bits(g_keys[2*t], g_keys[2*t+1], (unsigned)(b*Sz + tid));
    float u = __uint_as_float((bits >> 9) | 0x3f800000u) - 1.f;
    float gum = -logf(-logf(u + 1e-10f) + 1e-10f);
    y = lg + gum;
  }
  float by = y; int bi = tid; float bm = lg;
  #pragma unroll
  for (int off=32; off; off>>=1){
    float oy = __shfl_xor(by, off);
    int   oi = __shfl_xor(bi, off);
    float om = __shfl_xor(bm, off);
    if (oy > by || (oy == by && oi < bi)){ by = oy; bi = oi; }
    bm = fmaxf(bm, om);
  }
  if (lane64 == 0){ redy[wave] = by; redi[wave] = bi; redm[wave] = bm; }
  __syncthreads();
  float fy = redy[0]; int fi = redi[0]; float fm = redm[0];
  #pragma unroll
  for (int w=1; w<16; w++){
    if (redy[w] > fy || (redy[w] == fy && redi[w] < fi)){ fy = redy[w]; fi = redi[w]; }
    fm = fmaxf(fm, redm[w]);
  }
  int ptr = fi;

  float pe = (tid < Sz) ? expf(lg - fm) : 0.f;
  #pragma unroll
  for (int off=32; off; off>>=1) pe += __shfl_xor(pe, off);
  if (lane64 == 0) redsum[wave] = pe;
  __syncthreads();
  if (tid == 0){
    float den = 0.f;
    #pragma unroll
    for (int w=0; w<16; w++) den += redsum[w];
    float logp = slog[ptr] - fm - logf(den);
    out[(size_t)b*Sz + t] = (float)ptr;
    out[(size_t)Bz*Sz + (size_t)b*Sz + t] = logp;
    g_mask[b*Sz + ptr] = 1;
    g_ptrbuf[b] = ptr;
  }
}

// ---------------------------------------------------------------------------
extern "C" void kernel_launch(void* const* d_in, const int* in_sizes, int n_in,
                              void* d_out, int out_size, void* d_ws, size_t ws_size,
                              hipStream_t stream){
  (void)in_sizes; (void)n_in; (void)out_size; (void)d_ws; (void)ws_size;
  const float* embedding = (const float*)d_in[0];
  const float* enc_Wih = (const float*)d_in[1];
  const float* enc_Whh = (const float*)d_in[2];
  const float* enc_b   = (const float*)d_in[3];
  const float* dec_Wih = (const float*)d_in[4];
  const float* dec_Whh = (const float*)d_in[5];
  const float* dec_b   = (const float*)d_in[6];
  const float* pt_Wq   = (const float*)d_in[7];
  const float* pt_bq   = (const float*)d_in[8];
  const float* pt_Wref = (const float*)d_in[9];
  const float* pt_bref = (const float*)d_in[10];
  const float* pt_V    = (const float*)d_in[11];
  const float* gl_Wq   = (const float*)d_in[12];
  const float* gl_bq   = (const float*)d_in[13];
  const float* gl_Wref = (const float*)d_in[14];
  const float* gl_bref = (const float*)d_in[15];
  const float* gl_V    = (const float*)d_in[16];
  const float* dec_start = (const float*)d_in[17];
  const int*   inputs  = (const int*)d_in[18];
  float* out = (float*)d_out;

  init_kernel<<<512, 256, 0, stream>>>();
  xproj_kernel<<<dim3(256,8), 256, 0, stream>>>(enc_Wih, enc_b, embedding, dec_start, 0);
  xproj_kernel<<<dim3(257,8), 256, 0, stream>>>(dec_Wih, dec_b, embedding, dec_start, 1);

  // ---- encoder ----
  for (int t = 0; t < Sz; t++){
    lstm_step<<<dim3(8,32), 512, 0, stream>>>(enc_Whh, inputs, t, 0, t & 1);
  }
  // ---- ref projections ----
  gemm_ref<<<dim3(1024,8), 256, 0, stream>>>(gl_Wref, gl_bref, 1);
  gemm_ref<<<dim3(1024,8), 256, 0, stream>>>(pt_Wref, pt_bref, 2);

  // ---- decoder ----
  for (int t = 0; t < Sz; t++){
    lstm_step<<<dim3(8,32), 512, 0, stream>>>(dec_Whh, inputs, t, 1, t & 1);
    attn_step<<<Bz, 1024, 0, stream>>>(gl_Wq, gl_bq, gl_V,
        pt_Wq, pt_bq, pt_V, t, (t+1) & 1, out);
  }
}